// Round 12
// baseline (196.846 us; speedup 1.0000x reference)
//
#include <hip/hip_runtime.h>
#include <hip/hip_bf16.h>

#define N_TOK 65536
#define DIM 64
#define K_CODES 1024

typedef short short8 __attribute__((ext_vector_type(8)));
typedef __bf16 bf16x8 __attribute__((ext_vector_type(8)));
typedef float f32x4 __attribute__((ext_vector_type(4)));
typedef unsigned uintx4 __attribute__((ext_vector_type(4)));

static __device__ __forceinline__ short cvt_bf16(float x) {
    return __builtin_bit_cast(short, __float2bfloat16(x));
}

// Bank-conflict swizzle for the 128 KB bf16 B-tile (16B chunks within 2 KB).
static __device__ __forceinline__ int swz(int byte_off) {
    return byte_off ^ (((byte_off >> 8) & 7) << 4);
}

// ============================ REAL PIPELINE (r6 champion, verbatim) =========
__global__ __launch_bounds__(1024, 4) void vq_main(const float* __restrict__ lat,
                                                   const float* __restrict__ emb,
                                                   float* __restrict__ out,
                                                   float* __restrict__ partials) {
    __shared__ __align__(16) short lds_b[65536];      // 128 KB
    __shared__ float lds_cv[K_CODES];                 // 4 KB
    __shared__ __align__(16) unsigned lds_comb[1024]; // [row][h]
    __shared__ int lds_code[256];
    __shared__ float lds_lnp[16];
    __shared__ float lds_rl[4];

    const int tid  = threadIdx.x;
    const int lane = tid & 63;
    const int wave = tid >> 6;
    const int rg = wave >> 2;
    const int h  = wave & 3;
    const int c = lane & 15;
    const int g = lane >> 4;
    const int wrow0 = blockIdx.x * 256 + rg * 64;
    char* lds_bc = reinterpret_cast<char*>(lds_b);

    bf16x8 a[4][2];
    float lnp = 0.f;
#pragma unroll
    for (int m = 0; m < 4; ++m) {
        const f32x4* rp4 = reinterpret_cast<const f32x4*>(lat + (size_t)(wrow0 + m * 16 + c) * DIM);
        f32x4 p0 = rp4[g * 2], p1 = rp4[g * 2 + 1];
        f32x4 p2 = rp4[8 + g * 2], p3 = rp4[8 + g * 2 + 1];
        short8 t0, t1;
#pragma unroll
        for (int j = 0; j < 4; ++j) {
            lnp = fmaf(p0[j], p0[j], lnp); lnp = fmaf(p1[j], p1[j], lnp);
            lnp = fmaf(p2[j], p2[j], lnp); lnp = fmaf(p3[j], p3[j], lnp);
            t0[j] = cvt_bf16(p0[j]); t0[4 + j] = cvt_bf16(p1[j]);
            t1[j] = cvt_bf16(p2[j]); t1[4 + j] = cvt_bf16(p3[j]);
        }
        a[m][0] = __builtin_bit_cast(bf16x8, t0);
        a[m][1] = __builtin_bit_cast(bf16x8, t1);
    }
#pragma unroll
    for (int off = 1; off < 64; off <<= 1) lnp += __shfl_xor(lnp, off, 64);
    if (lane == 0) lds_lnp[wave] = lnp;

#pragma unroll
    for (int i = 0; i < 8; ++i) {
        const int u = i * 1024 + tid;
        const int code = u >> 3, d0 = (u & 7) * 8;
        f32x4 q0 = *reinterpret_cast<const f32x4*>(emb + (size_t)u * 8);
        f32x4 q1 = *reinterpret_cast<const f32x4*>(emb + (size_t)u * 8 + 4);
        float ns = 0.f;
        short8 v;
#pragma unroll
        for (int j = 0; j < 4; ++j) {
            ns = fmaf(q0[j], q0[j], ns); ns = fmaf(q1[j], q1[j], ns);
            v[j] = cvt_bf16(q0[j]); v[4 + j] = cvt_bf16(q1[j]);
        }
        ns += __shfl_xor(ns, 1, 64);
        ns += __shfl_xor(ns, 2, 64);
        ns += __shfl_xor(ns, 4, 64);
        const int f  = (code >> 4) * 2 + (d0 >> 5);
        const int lt = (code & 15) + ((d0 & 31) >> 3) * 16;
        *reinterpret_cast<short8*>(lds_bc + swz(f * 1024 + lt * 16)) = v;
        if ((u & 7) == 0) lds_cv[code] = 4.0f - 0.5f * ns;
    }

    unsigned pm[4][4];
#pragma unroll
    for (int m = 0; m < 4; ++m)
#pragma unroll
        for (int j = 0; j < 4; ++j) pm[m][j] = 0u;

    const int bbyte = h * 32768 + lane * 16;
    __syncthreads();

#pragma unroll 4
    for (int ti = 0; ti < 16; ++ti) {
        bf16x8 b0 = __builtin_bit_cast(bf16x8,
            *reinterpret_cast<const short8*>(lds_bc + swz(bbyte + ti * 2048)));
        bf16x8 b1 = __builtin_bit_cast(bf16x8,
            *reinterpret_cast<const short8*>(lds_bc + swz(bbyte + ti * 2048 + 1024)));
        const float cv = lds_cv[(h * 16 + ti) * 16 + c];
        const unsigned ib = 63u - (unsigned)ti;
#pragma unroll
        for (int m = 0; m < 4; ++m) {
            f32x4 acc = {cv, cv, cv, cv};
            acc = __builtin_amdgcn_mfma_f32_16x16x32_bf16(a[m][0], b0, acc, 0, 0, 0);
            acc = __builtin_amdgcn_mfma_f32_16x16x32_bf16(a[m][1], b1, acc, 0, 0, 0);
#pragma unroll
            for (int j = 0; j < 4; ++j) {
                unsigned ub = __builtin_bit_cast(unsigned, acc[j]);
                unsigned pv = (ub & 0xFFFFFFC0u) | ib;
                pm[m][j] = pm[m][j] < pv ? pv : pm[m][j];
            }
        }
    }

#pragma unroll
    for (int m = 0; m < 4; ++m) {
#pragma unroll
        for (int j = 0; j < 4; ++j) {
            unsigned v = pm[m][j];
            unsigned gcode = ((unsigned)h * 16u + (63u - (v & 63u))) * 16u + (unsigned)c;
            v = (v & 0xFFFFFC00u) | (1023u - gcode);
#pragma unroll
            for (int off = 1; off < 16; off <<= 1) {
                unsigned o = (unsigned)__shfl_xor((int)v, off, 64);
                v = v < o ? o : v;
            }
            pm[m][j] = v;
        }
    }
    if (c == 0) {
#pragma unroll
        for (int m = 0; m < 4; ++m)
#pragma unroll
            for (int j = 0; j < 4; ++j) {
                const int row = rg * 64 + m * 16 + g * 4 + j;
                lds_comb[row * 4 + h] = pm[m][j];
            }
    }
    __syncthreads();

    if (tid < 256) {
        uintx4 cm = *reinterpret_cast<const uintx4*>(&lds_comb[tid * 4]);
        unsigned v0 = cm[0] > cm[1] ? cm[0] : cm[1];
        unsigned v1 = cm[2] > cm[3] ? cm[2] : cm[3];
        unsigned v = v0 > v1 ? v0 : v1;
        lds_code[tid] = (int)(1023u - (v & 1023u));
        float tv = __builtin_bit_cast(float, v & 0xFFFFFC00u);
        float rl = fmaf(-2.0f, tv, 8.0f);
#pragma unroll
        for (int off = 1; off < 64; off <<= 1) rl += __shfl_xor(rl, off, 64);
        if (lane == 0) lds_rl[wave] = rl;
    }
    __syncthreads();

#pragma unroll
    for (int it = 0; it < 4; ++it) {
        const int cidx = it * 1024 + tid;
        const int row = cidx >> 4, seg = cidx & 15;
        const int gc = lds_code[row];
        reinterpret_cast<f32x4*>(out)[(size_t)(blockIdx.x * 256 + row) * 16 + seg] =
            reinterpret_cast<const f32x4*>(emb)[(size_t)gc * 16 + seg];
    }
    if (tid == 0) {
        partials[blockIdx.x] = lds_rl[0] + lds_rl[1] + lds_rl[2] + lds_rl[3]
                             + lds_lnp[0] + lds_lnp[4] + lds_lnp[8] + lds_lnp[12];
    }
}

__global__ __launch_bounds__(64) void vq_finalize(const float* __restrict__ partials,
                                                  float* __restrict__ loss_out) {
    const int lane = threadIdx.x;
    f32x4 p4 = reinterpret_cast<const f32x4*>(partials)[lane];
    float p = (p4[0] + p4[1]) + (p4[2] + p4[3]);
#pragma unroll
    for (int off = 1; off < 64; off <<= 1) p += __shfl_xor(p, off, 64);
    if (lane == 0) loss_out[0] = p * (1.25f / 4194304.f);
}

// ============================ ABLATION PROBES (scratch-only writes) =========
// Probe 1: full r6 body x REP, gather -> scratch_out, partial -> checksum.
template <int REP>
__global__ __launch_bounds__(1024, 4) void vq_probe_full(const float* __restrict__ lat,
                                                         const float* __restrict__ emb,
                                                         float* __restrict__ scratch_out,
                                                         float* __restrict__ cksum) {
    __shared__ __align__(16) short lds_b[65536];
    __shared__ float lds_cv[K_CODES];
    __shared__ __align__(16) unsigned lds_comb[1024];
    __shared__ int lds_code[256];
    __shared__ float lds_lnp[16];
    __shared__ float lds_rl[4];

    const int tid  = threadIdx.x;
    const int lane = tid & 63;
    const int wave = tid >> 6;
    const int rg = wave >> 2;
    const int h  = wave & 3;
    const int c = lane & 15;
    const int g = lane >> 4;
    const int wrow0 = blockIdx.x * 256 + rg * 64;
    char* lds_bc = reinterpret_cast<char*>(lds_b);
    float total = 0.f;

    for (int rep = 0; rep < REP; ++rep) {
        bf16x8 a[4][2];
        float lnp = 0.f;
#pragma unroll
        for (int m = 0; m < 4; ++m) {
            const f32x4* rp4 = reinterpret_cast<const f32x4*>(lat + (size_t)(wrow0 + m * 16 + c) * DIM);
            f32x4 p0 = rp4[g * 2], p1 = rp4[g * 2 + 1];
            f32x4 p2 = rp4[8 + g * 2], p3 = rp4[8 + g * 2 + 1];
            short8 t0, t1;
#pragma unroll
            for (int j = 0; j < 4; ++j) {
                lnp = fmaf(p0[j], p0[j], lnp); lnp = fmaf(p1[j], p1[j], lnp);
                lnp = fmaf(p2[j], p2[j], lnp); lnp = fmaf(p3[j], p3[j], lnp);
                t0[j] = cvt_bf16(p0[j]); t0[4 + j] = cvt_bf16(p1[j]);
                t1[j] = cvt_bf16(p2[j]); t1[4 + j] = cvt_bf16(p3[j]);
            }
            a[m][0] = __builtin_bit_cast(bf16x8, t0);
            a[m][1] = __builtin_bit_cast(bf16x8, t1);
        }
#pragma unroll
        for (int off = 1; off < 64; off <<= 1) lnp += __shfl_xor(lnp, off, 64);
        if (lane == 0) lds_lnp[wave] = lnp;

#pragma unroll
        for (int i = 0; i < 8; ++i) {
            const int u = i * 1024 + tid;
            const int code = u >> 3, d0 = (u & 7) * 8;
            f32x4 q0 = *reinterpret_cast<const f32x4*>(emb + (size_t)u * 8);
            f32x4 q1 = *reinterpret_cast<const f32x4*>(emb + (size_t)u * 8 + 4);
            float ns = 0.f;
            short8 v;
#pragma unroll
            for (int j = 0; j < 4; ++j) {
                ns = fmaf(q0[j], q0[j], ns); ns = fmaf(q1[j], q1[j], ns);
                v[j] = cvt_bf16(q0[j]); v[4 + j] = cvt_bf16(q1[j]);
            }
            ns += __shfl_xor(ns, 1, 64);
            ns += __shfl_xor(ns, 2, 64);
            ns += __shfl_xor(ns, 4, 64);
            const int f  = (code >> 4) * 2 + (d0 >> 5);
            const int lt = (code & 15) + ((d0 & 31) >> 3) * 16;
            *reinterpret_cast<short8*>(lds_bc + swz(f * 1024 + lt * 16)) = v;
            if ((u & 7) == 0) lds_cv[code] = 4.0f - 0.5f * ns;
        }

        unsigned pm[4][4];
#pragma unroll
        for (int m = 0; m < 4; ++m)
#pragma unroll
            for (int j = 0; j < 4; ++j) pm[m][j] = 0u;
        const int bbyte = h * 32768 + lane * 16;
        __syncthreads();

#pragma unroll 4
        for (int ti = 0; ti < 16; ++ti) {
            bf16x8 b0 = __builtin_bit_cast(bf16x8,
                *reinterpret_cast<const short8*>(lds_bc + swz(bbyte + ti * 2048)));
            bf16x8 b1 = __builtin_bit_cast(bf16x8,
                *reinterpret_cast<const short8*>(lds_bc + swz(bbyte + ti * 2048 + 1024)));
            const float cv = lds_cv[(h * 16 + ti) * 16 + c];
            const unsigned ib = 63u - (unsigned)ti;
#pragma unroll
            for (int m = 0; m < 4; ++m) {
                f32x4 acc = {cv, cv, cv, cv};
                acc = __builtin_amdgcn_mfma_f32_16x16x32_bf16(a[m][0], b0, acc, 0, 0, 0);
                acc = __builtin_amdgcn_mfma_f32_16x16x32_bf16(a[m][1], b1, acc, 0, 0, 0);
#pragma unroll
                for (int j = 0; j < 4; ++j) {
                    unsigned ub = __builtin_bit_cast(unsigned, acc[j]);
                    unsigned pv = (ub & 0xFFFFFFC0u) | ib;
                    pm[m][j] = pm[m][j] < pv ? pv : pm[m][j];
                }
            }
        }

#pragma unroll
        for (int m = 0; m < 4; ++m) {
#pragma unroll
            for (int j = 0; j < 4; ++j) {
                unsigned v = pm[m][j];
                unsigned gcode = ((unsigned)h * 16u + (63u - (v & 63u))) * 16u + (unsigned)c;
                v = (v & 0xFFFFFC00u) | (1023u - gcode);
#pragma unroll
                for (int off = 1; off < 16; off <<= 1) {
                    unsigned o = (unsigned)__shfl_xor((int)v, off, 64);
                    v = v < o ? o : v;
                }
                pm[m][j] = v;
            }
        }
        if (c == 0) {
#pragma unroll
            for (int m = 0; m < 4; ++m)
#pragma unroll
                for (int j = 0; j < 4; ++j)
                    lds_comb[(rg * 64 + m * 16 + g * 4 + j) * 4 + h] = pm[m][j];
        }
        __syncthreads();

        if (tid < 256) {
            uintx4 cm = *reinterpret_cast<const uintx4*>(&lds_comb[tid * 4]);
            unsigned v0 = cm[0] > cm[1] ? cm[0] : cm[1];
            unsigned v1 = cm[2] > cm[3] ? cm[2] : cm[3];
            unsigned v = v0 > v1 ? v0 : v1;
            lds_code[tid] = (int)(1023u - (v & 1023u));
            float tv = __builtin_bit_cast(float, v & 0xFFFFFC00u);
            float rl = fmaf(-2.0f, tv, 8.0f);
#pragma unroll
            for (int off = 1; off < 64; off <<= 1) rl += __shfl_xor(rl, off, 64);
            if (lane == 0) lds_rl[wave] = rl;
        }
        __syncthreads();

#pragma unroll
        for (int it = 0; it < 4; ++it) {
            const int cidx = it * 1024 + tid;
            const int row = cidx >> 4, seg = cidx & 15;
            const int gc = lds_code[row];
            reinterpret_cast<f32x4*>(scratch_out)[(size_t)(blockIdx.x * 256 + row) * 16 + seg] =
                reinterpret_cast<const f32x4*>(emb)[(size_t)gc * 16 + seg];
        }
        total += lds_rl[0] + lds_lnp[0];
        __syncthreads();
        asm volatile("" ::: "memory");
    }
    if (tid == 0) cksum[blockIdx.x] = total;
}

// Probe 2: stage + K-loop only (dummy A-frags), x REP.
template <int REP>
__global__ __launch_bounds__(1024, 4) void vq_probe_kstage(const float* __restrict__ emb,
                                                           float* __restrict__ cksum) {
    __shared__ __align__(16) short lds_b[65536];
    __shared__ float lds_cv[K_CODES];
    const int tid  = threadIdx.x;
    const int lane = tid & 63;
    const int wave = tid >> 6;
    const int h  = wave & 3;
    const int c = lane & 15;
    char* lds_bc = reinterpret_cast<char*>(lds_b);

    bf16x8 a[4][2];
#pragma unroll
    for (int m = 0; m < 4; ++m)
#pragma unroll
        for (int s = 0; s < 2; ++s) {
            short8 t;
#pragma unroll
            for (int j = 0; j < 8; ++j) t[j] = cvt_bf16((float)((tid + m * 3 + s + j) & 7));
            a[m][s] = __builtin_bit_cast(bf16x8, t);
        }

    unsigned pmt = 0u;
    for (int rep = 0; rep < REP; ++rep) {
#pragma unroll
        for (int i = 0; i < 8; ++i) {
            const int u = i * 1024 + tid;
            const int code = u >> 3, d0 = (u & 7) * 8;
            f32x4 q0 = *reinterpret_cast<const f32x4*>(emb + (size_t)u * 8);
            f32x4 q1 = *reinterpret_cast<const f32x4*>(emb + (size_t)u * 8 + 4);
            float ns = 0.f;
            short8 v;
#pragma unroll
            for (int j = 0; j < 4; ++j) {
                ns = fmaf(q0[j], q0[j], ns); ns = fmaf(q1[j], q1[j], ns);
                v[j] = cvt_bf16(q0[j]); v[4 + j] = cvt_bf16(q1[j]);
            }
            ns += __shfl_xor(ns, 1, 64);
            ns += __shfl_xor(ns, 2, 64);
            ns += __shfl_xor(ns, 4, 64);
            const int f  = (code >> 4) * 2 + (d0 >> 5);
            const int lt = (code & 15) + ((d0 & 31) >> 3) * 16;
            *reinterpret_cast<short8*>(lds_bc + swz(f * 1024 + lt * 16)) = v;
            if ((u & 7) == 0) lds_cv[code] = 4.0f - 0.5f * ns;
        }
        unsigned pm[4][4];
#pragma unroll
        for (int m = 0; m < 4; ++m)
#pragma unroll
            for (int j = 0; j < 4; ++j) pm[m][j] = 0u;
        const int bbyte = h * 32768 + lane * 16;
        __syncthreads();
#pragma unroll 4
        for (int ti = 0; ti < 16; ++ti) {
            bf16x8 b0 = __builtin_bit_cast(bf16x8,
                *reinterpret_cast<const short8*>(lds_bc + swz(bbyte + ti * 2048)));
            bf16x8 b1 = __builtin_bit_cast(bf16x8,
                *reinterpret_cast<const short8*>(lds_bc + swz(bbyte + ti * 2048 + 1024)));
            const float cv = lds_cv[(h * 16 + ti) * 16 + c];
            const unsigned ib = 63u - (unsigned)ti;
#pragma unroll
            for (int m = 0; m < 4; ++m) {
                f32x4 acc = {cv, cv, cv, cv};
                acc = __builtin_amdgcn_mfma_f32_16x16x32_bf16(a[m][0], b0, acc, 0, 0, 0);
                acc = __builtin_amdgcn_mfma_f32_16x16x32_bf16(a[m][1], b1, acc, 0, 0, 0);
#pragma unroll
                for (int j = 0; j < 4; ++j) {
                    unsigned ub = __builtin_bit_cast(unsigned, acc[j]);
                    unsigned pv = (ub & 0xFFFFFFC0u) | ib;
                    pm[m][j] = pm[m][j] < pv ? pv : pm[m][j];
                }
            }
        }
#pragma unroll
        for (int m = 0; m < 4; ++m)
#pragma unroll
            for (int j = 0; j < 4; ++j) pmt = pmt < pm[m][j] ? pm[m][j] : pmt;
        __syncthreads();
        asm volatile("" ::: "memory");
    }
    if (lane == 0) cksum[blockIdx.x * 16 + wave] = (float)pmt;
}

// Probe 3: A-load + convert + lnp only, x REP (128 KB LDS pad -> 1 block/CU).
template <int REP>
__global__ __launch_bounds__(1024, 4) void vq_probe_aload(const float* __restrict__ lat,
                                                          float* __restrict__ cksum) {
    __shared__ char pad[131072];
    const int tid  = threadIdx.x;
    const int lane = tid & 63;
    const int wave = tid >> 6;
    const int rg = wave >> 2;
    const int c = lane & 15;
    const int g = lane >> 4;
    const int wrow0 = blockIdx.x * 256 + rg * 64;
    pad[tid] = 0;
    float total = 0.f;

    for (int rep = 0; rep < REP; ++rep) {
        bf16x8 a[4][2];
        float lnp = 0.f;
#pragma unroll
        for (int m = 0; m < 4; ++m) {
            const f32x4* rp4 = reinterpret_cast<const f32x4*>(lat + (size_t)(wrow0 + m * 16 + c) * DIM);
            f32x4 p0 = rp4[g * 2], p1 = rp4[g * 2 + 1];
            f32x4 p2 = rp4[8 + g * 2], p3 = rp4[8 + g * 2 + 1];
            short8 t0, t1;
#pragma unroll
            for (int j = 0; j < 4; ++j) {
                lnp = fmaf(p0[j], p0[j], lnp); lnp = fmaf(p1[j], p1[j], lnp);
                lnp = fmaf(p2[j], p2[j], lnp); lnp = fmaf(p3[j], p3[j], lnp);
                t0[j] = cvt_bf16(p0[j]); t0[4 + j] = cvt_bf16(p1[j]);
                t1[j] = cvt_bf16(p2[j]); t1[4 + j] = cvt_bf16(p3[j]);
            }
            a[m][0] = __builtin_bit_cast(bf16x8, t0);
            a[m][1] = __builtin_bit_cast(bf16x8, t1);
        }
#pragma unroll
        for (int off = 1; off < 64; off <<= 1) lnp += __shfl_xor(lnp, off, 64);
        total += lnp + (float)__builtin_bit_cast(short8, a[0][0])[0];
        asm volatile("" ::: "memory");
    }
    if (lane == 0) cksum[blockIdx.x * 16 + wave] = total + (float)pad[tid & 0];
}

extern "C" void kernel_launch(void* const* d_in, const int* in_sizes, int n_in,
                              void* d_out, int out_size, void* d_ws, size_t ws_size,
                              hipStream_t stream) {
    const float* lat = (const float*)d_in[0];
    const float* emb = (const float*)d_in[1];
    float* out = (float*)d_out;
    float* partials = (float*)d_ws;                            // [0, 1KB)
    float* cksum = (float*)((char*)d_ws + (1 << 20));          // +1 MB
    float* scratch_out = (float*)((char*)d_ws + (8u << 20));   // +8 MB (16.8 MB)

    // real pipeline (r6 champion)
    vq_main<<<256, 1024, 0, stream>>>(lat, emb, out, partials);
    vq_finalize<<<1, 64, 0, stream>>>(partials, out + (size_t)N_TOK * DIM);

    // ablation probes (write scratch only; REP-inflated to surface in rocprof top-5)
    vq_probe_full<4><<<256, 1024, 0, stream>>>(lat, emb, scratch_out, cksum);
    vq_probe_kstage<8><<<256, 1024, 0, stream>>>(emb, cksum + 65536);
    vq_probe_aload<32><<<256, 1024, 0, stream>>>(lat, cksum + 131072);
}

// Round 13
// 47.373 us; speedup vs baseline: 4.1552x; 4.1552x over previous
//
#include <hip/hip_runtime.h>
#include <hip/hip_bf16.h>

#define N_TOK 65536
#define DIM 64
#define K_CODES 1024

typedef short short8 __attribute__((ext_vector_type(8)));
typedef __bf16 bf16x8 __attribute__((ext_vector_type(8)));
typedef float f32x4 __attribute__((ext_vector_type(4)));
typedef unsigned uintx4 __attribute__((ext_vector_type(4)));

static __device__ __forceinline__ short cvt_bf16(float x) {
    return __builtin_bit_cast(short, __float2bfloat16(x));
}

// Bank-conflict swizzle for the bf16 B-tile (16B chunks within 2 KB windows).
static __device__ __forceinline__ int swz(int byte_off) {
    return byte_off ^ (((byte_off >> 8) & 7) << 4);
}

// Kernel1: argmin partials over HALF the codebook. Grid 512 = (row-tile 0..255,
// kb 0..1); block = 1024 thr = 16 waves; wave (rg = w>>2, h = w&3): rows
// rg*64..+63 (4 m-tiles) vs 8 tiles of the half's 32. LDS ~72 KB -> 2 blocks/CU
// (the two co-resident blocks' phases overlap; each stages only its half).
// Packing (r6-verified): maximize tv = <l,e>_bf16 + 4 - ||e||^2/2 > 0; in-loop
// (bits&~63)|(63-ti); repack (bits&~1023)|(1023-gcode); max_u32. Per row-half
// winner -> pmbuf[kb*65536 + row]. lnp (exact f32 ||l||^2) -> partials1 (kb==0).
__global__ __launch_bounds__(1024, 8) void vq_k1(const float* __restrict__ lat,
                                                 const float* __restrict__ emb,
                                                 unsigned* __restrict__ pmbuf,
                                                 float* __restrict__ partials1) {
    __shared__ __align__(16) short lds_b[32768];      // 64 KB: half codebook
    __shared__ float lds_cv[512];                     // 2 KB
    __shared__ __align__(16) unsigned lds_comb[1024]; // [row 0..255][h]
    __shared__ float lds_lnp[16];

    const int tid  = threadIdx.x;
    const int lane = tid & 63;
    const int wave = tid >> 6;
    const int rg = wave >> 2;
    const int h  = wave & 3;
    const int c = lane & 15;
    const int g = lane >> 4;
    const int kb   = blockIdx.x >> 8;     // codebook half
    const int bidr = blockIdx.x & 255;    // row tile
    const int wrow0 = bidr * 256 + rg * 64;
    char* lds_bc = reinterpret_cast<char*>(lds_b);

    // A-fragments (4 m-tiles of 16 rows) + exact f32 ||l||^2 partial
    bf16x8 a[4][2];
    float lnp = 0.f;
#pragma unroll
    for (int m = 0; m < 4; ++m) {
        const f32x4* rp4 = reinterpret_cast<const f32x4*>(lat + (size_t)(wrow0 + m * 16 + c) * DIM);
        f32x4 p0 = rp4[g * 2], p1 = rp4[g * 2 + 1];
        f32x4 p2 = rp4[8 + g * 2], p3 = rp4[8 + g * 2 + 1];
        short8 t0, t1;
#pragma unroll
        for (int j = 0; j < 4; ++j) {
            lnp = fmaf(p0[j], p0[j], lnp); lnp = fmaf(p1[j], p1[j], lnp);
            lnp = fmaf(p2[j], p2[j], lnp); lnp = fmaf(p3[j], p3[j], lnp);
            t0[j] = cvt_bf16(p0[j]); t0[4 + j] = cvt_bf16(p1[j]);
            t1[j] = cvt_bf16(p2[j]); t1[4 + j] = cvt_bf16(p3[j]);
        }
        a[m][0] = __builtin_bit_cast(bf16x8, t0);
        a[m][1] = __builtin_bit_cast(bf16x8, t1);
    }
#pragma unroll
    for (int off = 1; off < 64; off <<= 1) lnp += __shfl_xor(lnp, off, 64);
    if (lane == 0) lds_lnp[wave] = lnp;

    // Stage this half: u in [0,4096) covers 512 codes x 64 dims, 8 f32/thread.
#pragma unroll
    for (int i = 0; i < 4; ++i) {
        const int u = i * 1024 + tid;
        const int code = u >> 3, d0 = (u & 7) * 8;   // code: half-local 0..511
        const float* src = emb + (size_t)kb * 32768 + (size_t)u * 8;
        f32x4 q0 = *reinterpret_cast<const f32x4*>(src);
        f32x4 q1 = *reinterpret_cast<const f32x4*>(src + 4);
        float ns = 0.f;
        short8 v;
#pragma unroll
        for (int j = 0; j < 4; ++j) {
            ns = fmaf(q0[j], q0[j], ns); ns = fmaf(q1[j], q1[j], ns);
            v[j] = cvt_bf16(q0[j]); v[4 + j] = cvt_bf16(q1[j]);
        }
        ns += __shfl_xor(ns, 1, 64);
        ns += __shfl_xor(ns, 2, 64);
        ns += __shfl_xor(ns, 4, 64);
        const int f  = (code >> 4) * 2 + (d0 >> 5);
        const int lt = (code & 15) + ((d0 & 31) >> 3) * 16;
        *reinterpret_cast<short8*>(lds_bc + swz(f * 1024 + lt * 16)) = v;
        if ((u & 7) == 0) lds_cv[code] = 4.0f - 0.5f * ns;
    }

    unsigned pm[4][4];
#pragma unroll
    for (int m = 0; m < 4; ++m)
#pragma unroll
        for (int j = 0; j < 4; ++j) pm[m][j] = 0u;

    const int bbyte = h * 16384 + lane * 16;
    __syncthreads();

#pragma unroll
    for (int ti = 0; ti < 8; ++ti) {
        bf16x8 b0 = __builtin_bit_cast(bf16x8,
            *reinterpret_cast<const short8*>(lds_bc + swz(bbyte + ti * 2048)));
        bf16x8 b1 = __builtin_bit_cast(bf16x8,
            *reinterpret_cast<const short8*>(lds_bc + swz(bbyte + ti * 2048 + 1024)));
        const float cv = lds_cv[(h * 8 + ti) * 16 + c];
        const unsigned ib = 63u - (unsigned)ti;
#pragma unroll
        for (int m = 0; m < 4; ++m) {
            f32x4 acc = {cv, cv, cv, cv};
            acc = __builtin_amdgcn_mfma_f32_16x16x32_bf16(a[m][0], b0, acc, 0, 0, 0);
            acc = __builtin_amdgcn_mfma_f32_16x16x32_bf16(a[m][1], b1, acc, 0, 0, 0);
#pragma unroll
            for (int j = 0; j < 4; ++j) {
                unsigned ub = __builtin_bit_cast(unsigned, acc[j]);
                unsigned pv = (ub & 0xFFFFFFC0u) | ib;
                pm[m][j] = pm[m][j] < pv ? pv : pm[m][j];
            }
        }
    }

    // repack with 10-bit GLOBAL code, 16-lane shfl max (max at all lanes)
#pragma unroll
    for (int m = 0; m < 4; ++m) {
#pragma unroll
        for (int j = 0; j < 4; ++j) {
            unsigned v = pm[m][j];
            unsigned tl = 63u - (v & 63u);                      // 0..7 local tile
            unsigned gcode = (unsigned)(kb * 512) + ((unsigned)h * 8u + tl) * 16u + (unsigned)c;
            v = (v & 0xFFFFFC00u) | (1023u - gcode);
#pragma unroll
            for (int off = 1; off < 16; off <<= 1) {
                unsigned o = (unsigned)__shfl_xor((int)v, off, 64);
                v = v < o ? o : v;
            }
            pm[m][j] = v;
        }
    }
    if (c == 0) {
#pragma unroll
        for (int m = 0; m < 4; ++m)
#pragma unroll
            for (int j = 0; j < 4; ++j) {
                const int row = rg * 64 + m * 16 + g * 4 + j;
                lds_comb[row * 4 + h] = pm[m][j];
            }
    }
    __syncthreads();

    // combine across h; one u32 winner per row-half -> pmbuf
    if (tid < 256) {
        uintx4 cm = *reinterpret_cast<const uintx4*>(&lds_comb[tid * 4]);
        unsigned v0 = cm[0] > cm[1] ? cm[0] : cm[1];
        unsigned v1 = cm[2] > cm[3] ? cm[2] : cm[3];
        unsigned v = v0 > v1 ? v0 : v1;
        pmbuf[(size_t)kb * N_TOK + bidr * 256 + tid] = v;
    }
    if (kb == 0 && tid == 0) {
        partials1[bidr] = lds_lnp[0] + lds_lnp[4] + lds_lnp[8] + lds_lnp[12];
    }
}

// Kernel2: merge halves, gather output rows, rl loss partials. 1024 blocks x
// 1024 thr (4 blocks/CU, pure memory). Thread -> (row = bid*64 + tid/16,
// seg = tid&15): v = max(half0, half1); code = 1023 - (v&1023);
// out[row][seg] = emb[code][seg] (16B, coalesced per row); rl at seg==0.
__global__ __launch_bounds__(1024, 8) void vq_k2(const float* __restrict__ emb,
                                                 const unsigned* __restrict__ pmbuf,
                                                 float* __restrict__ out,
                                                 float* __restrict__ partials2) {
    __shared__ float lds_rl[16];
    const int tid  = threadIdx.x;
    const int lane = tid & 63;
    const int wave = tid >> 6;
    const int row = blockIdx.x * 64 + (tid >> 4);
    const int seg = tid & 15;

    unsigned w0 = pmbuf[row];
    unsigned w1 = pmbuf[N_TOK + row];
    unsigned v = w0 > w1 ? w0 : w1;
    unsigned gcode = 1023u - (v & 1023u);

    f32x4 e4 = reinterpret_cast<const f32x4*>(emb)[(size_t)gcode * 16 + seg];
    reinterpret_cast<f32x4*>(out)[(size_t)row * 16 + seg] = e4;

    float rl = 0.f;
    if (seg == 0) {
        float tv = __builtin_bit_cast(float, v & 0xFFFFFC00u);
        rl = fmaf(-2.0f, tv, 8.0f);   // ||q-l||^2 - ||l||^2 for this row
    }
#pragma unroll
    for (int off = 1; off < 64; off <<= 1) rl += __shfl_xor(rl, off, 64);
    if (lane == 0) lds_rl[wave] = rl;
    __syncthreads();
    if (tid == 0) {
        float s = 0.f;
#pragma unroll
        for (int w = 0; w < 16; ++w) s += lds_rl[w];
        partials2[blockIdx.x] = s;
    }
}

// Finalize: sum 256 lnp partials + 1024 rl partials in fixed order.
__global__ __launch_bounds__(64) void vq_fin(const float* __restrict__ partials1,
                                             const float* __restrict__ partials2,
                                             float* __restrict__ loss_out) {
    const int lane = threadIdx.x;
    float p = 0.f;
    f32x4 a4 = reinterpret_cast<const f32x4*>(partials1)[lane];
    p += (a4[0] + a4[1]) + (a4[2] + a4[3]);
#pragma unroll
    for (int k = 0; k < 4; ++k) {
        f32x4 b4 = reinterpret_cast<const f32x4*>(partials2)[lane * 4 + k];
        p += (b4[0] + b4[1]) + (b4[2] + b4[3]);
    }
#pragma unroll
    for (int off = 1; off < 64; off <<= 1) p += __shfl_xor(p, off, 64);
    if (lane == 0) loss_out[0] = p * (1.25f / 4194304.f);
}

extern "C" void kernel_launch(void* const* d_in, const int* in_sizes, int n_in,
                              void* d_out, int out_size, void* d_ws, size_t ws_size,
                              hipStream_t stream) {
    const float* lat = (const float*)d_in[0];
    const float* emb = (const float*)d_in[1];
    float* out = (float*)d_out;
    unsigned* pmbuf = (unsigned*)d_ws;                         // 512 KB
    float* partials1 = (float*)((char*)d_ws + (512 << 10));    // 1 KB
    float* partials2 = (float*)((char*)d_ws + (516 << 10));    // 4 KB

    vq_k1<<<512, 1024, 0, stream>>>(lat, emb, pmbuf, partials1);
    vq_k2<<<1024, 1024, 0, stream>>>(emb, pmbuf, out, partials2);
    vq_fin<<<1, 64, 0, stream>>>(partials1, partials2, out + (size_t)N_TOK * DIM);
}

// Round 14
// 32.228 us; speedup vs baseline: 6.1080x; 1.4699x over previous
//
#include <hip/hip_runtime.h>
#include <hip/hip_bf16.h>

#define N_TOK 65536
#define DIM 64
#define K_CODES 1024

typedef short short8 __attribute__((ext_vector_type(8)));
typedef __bf16 bf16x8 __attribute__((ext_vector_type(8)));
typedef float f32x4 __attribute__((ext_vector_type(4)));
typedef unsigned uintx4 __attribute__((ext_vector_type(4)));

static __device__ __forceinline__ short cvt_bf16(float x) {
    return __builtin_bit_cast(short, __float2bfloat16(x));
}

// ws layout (bytes): [0,1K) per-block loss partials f32[256];
// [4096, 4096+4096) cvec_t f32[1024]: cvec_t[(code&15)*64 + (code>>4)] =
//   4 - ||e||^2/2 (exact f32);
// [8192, 8192+131072) bf16 B-fragments, consumer-linear: frag f = tile*2 + s
//   holds B[k][col] = emb[tile*16 + (lane&15)][s*32 + (lane>>4)*8 + j]
//   at byte f*1024 + lane*16. Main DMAs this verbatim into LDS.
__global__ __launch_bounds__(128) void vq_prep(const float* __restrict__ emb,
                                               float* __restrict__ cvec_t,
                                               short* __restrict__ bfrag) {
    const int u = blockIdx.x * 128 + threadIdx.x;   // 0..8191
    const int code = u >> 3, d0 = (u & 7) * 8;
    f32x4 q0 = *reinterpret_cast<const f32x4*>(emb + (size_t)u * 8);
    f32x4 q1 = *reinterpret_cast<const f32x4*>(emb + (size_t)u * 8 + 4);
    float ns = 0.f;
    short8 v;
#pragma unroll
    for (int j = 0; j < 4; ++j) {
        ns = fmaf(q0[j], q0[j], ns); ns = fmaf(q1[j], q1[j], ns);
        v[j] = cvt_bf16(q0[j]); v[4 + j] = cvt_bf16(q1[j]);
    }
    // 8-group sum, xor butterfly -> valid at ALL lanes (no direction hazard)
    ns += __shfl_xor(ns, 1, 64);
    ns += __shfl_xor(ns, 2, 64);
    ns += __shfl_xor(ns, 4, 64);
    const int f  = (code >> 4) * 2 + (d0 >> 5);
    const int lt = (code & 15) + ((d0 & 31) >> 3) * 16;
    *reinterpret_cast<short8*>(bfrag + (size_t)f * 512 + (size_t)lt * 8) = v;
    if ((u & 7) == 0)
        cvec_t[(code & 15) * 64 + (code >> 4)] = 4.0f - 0.5f * ns;
}

// Main: 256 blocks x 1024 threads (16 waves, 1 block/CU). r6-verified compute
// structure; staging replaced by async global_load_lds DMA (no VALU, no
// ds_write, no bank conflicts -> swizzle removed), A-loads pre-issued so HBM
// latency drains at the same barrier, code norms preloaded to 16 VGPRs from
// L2. Argmin maximizes tv = <l,e>_bf16 + 4 - ||e||^2/2 (> 0), tile bits in
// low mantissa under max_u32 (r6-verified packing). Loss row term =
// 8 - 2*tv + ||l||^2; per-block partial -> partials[] (no atomics).
__global__ __launch_bounds__(1024, 4) void vq_main(const float* __restrict__ lat,
                                                   const float* __restrict__ emb,
                                                   const float* __restrict__ cvec_t,
                                                   const short* __restrict__ bfrag,
                                                   float* __restrict__ out,
                                                   float* __restrict__ partials) {
    __shared__ __align__(16) short lds_b[65536];      // 128 KB B-tile
    __shared__ __align__(16) unsigned lds_comb[1024]; // [row 0..255][h]
    __shared__ int lds_code[256];
    __shared__ float lds_lnp[16];
    __shared__ float lds_rl[4];

    const int tid  = threadIdx.x;
    const int lane = tid & 63;
    const int wave = tid >> 6;
    const int rg = wave >> 2;
    const int h  = wave & 3;
    const int c = lane & 15;
    const int g = lane >> 4;
    const int wrow0 = blockIdx.x * 256 + rg * 64;
    char* lds_bc = reinterpret_cast<char*>(lds_b);

    // (1) issue A-loads: 16 dwordx4 pending (latency hides under DMA drain)
    f32x4 p[4][4];
#pragma unroll
    for (int m = 0; m < 4; ++m) {
        const f32x4* rp4 = reinterpret_cast<const f32x4*>(lat + (size_t)(wrow0 + m * 16 + c) * DIM);
        p[m][0] = rp4[g * 2];
        p[m][1] = rp4[g * 2 + 1];
        p[m][2] = rp4[8 + g * 2];
        p[m][3] = rp4[8 + g * 2 + 1];
    }

    // (2) async DMA stage: 128 KB, each wave 8 x 1KB (lane*16 linear dest)
#pragma unroll
    for (int i = 0; i < 8; ++i) {
        const int off = wave * 8192 + i * 1024;
        __builtin_amdgcn_global_load_lds(
            (const __attribute__((address_space(1))) void*)
                (reinterpret_cast<const char*>(bfrag) + off + lane * 16),
            (__attribute__((address_space(3))) void*)(lds_bc + off),
            16, 0, 0);
    }
    __syncthreads();   // drains A-loads AND DMA

    // (3) convert A to bf16 fragments + exact f32 ||l||^2 partial
    bf16x8 a[4][2];
    float lnp = 0.f;
#pragma unroll
    for (int m = 0; m < 4; ++m) {
        short8 t0, t1;
#pragma unroll
        for (int j = 0; j < 4; ++j) {
            lnp = fmaf(p[m][0][j], p[m][0][j], lnp);
            lnp = fmaf(p[m][1][j], p[m][1][j], lnp);
            lnp = fmaf(p[m][2][j], p[m][2][j], lnp);
            lnp = fmaf(p[m][3][j], p[m][3][j], lnp);
            t0[j] = cvt_bf16(p[m][0][j]); t0[4 + j] = cvt_bf16(p[m][1][j]);
            t1[j] = cvt_bf16(p[m][2][j]); t1[4 + j] = cvt_bf16(p[m][3][j]);
        }
        a[m][0] = __builtin_bit_cast(bf16x8, t0);
        a[m][1] = __builtin_bit_cast(bf16x8, t1);
    }
#pragma unroll
    for (int off = 1; off < 64; off <<= 1) lnp += __shfl_xor(lnp, off, 64);
    if (lane == 0) lds_lnp[wave] = lnp;

    // (4) preload this lane's 16 code-norm constants from L2 (broadcast-hot)
    f32x4 cvreg[4];
    {
        const f32x4* cvp = reinterpret_cast<const f32x4*>(cvec_t + c * 64 + h * 16);
        cvreg[0] = cvp[0]; cvreg[1] = cvp[1]; cvreg[2] = cvp[2]; cvreg[3] = cvp[3];
    }

    unsigned pm[4][4];
#pragma unroll
    for (int m = 0; m < 4; ++m)
#pragma unroll
        for (int j = 0; j < 4; ++j) pm[m][j] = 0u;

    const int bbyte = h * 32768 + lane * 16;

    // (5) K-loop: 16 tiles x 4 m-tiles (r6-verified core, linear LDS reads)
#pragma unroll 4
    for (int ti = 0; ti < 16; ++ti) {
        bf16x8 b0 = __builtin_bit_cast(bf16x8,
            *reinterpret_cast<const short8*>(lds_bc + bbyte + ti * 2048));
        bf16x8 b1 = __builtin_bit_cast(bf16x8,
            *reinterpret_cast<const short8*>(lds_bc + bbyte + ti * 2048 + 1024));
        const float cv = cvreg[ti >> 2][ti & 3];
        const unsigned ib = 63u - (unsigned)ti;
#pragma unroll
        for (int m = 0; m < 4; ++m) {
            f32x4 acc = {cv, cv, cv, cv};
            acc = __builtin_amdgcn_mfma_f32_16x16x32_bf16(a[m][0], b0, acc, 0, 0, 0);
            acc = __builtin_amdgcn_mfma_f32_16x16x32_bf16(a[m][1], b1, acc, 0, 0, 0);
#pragma unroll
            for (int j = 0; j < 4; ++j) {
                unsigned ub = __builtin_bit_cast(unsigned, acc[j]);
                unsigned pv = (ub & 0xFFFFFFC0u) | ib;
                pm[m][j] = pm[m][j] < pv ? pv : pm[m][j];
            }
        }
    }

    // (6) repack with 10-bit global code; 16-lane xor-max (valid at all lanes)
#pragma unroll
    for (int m = 0; m < 4; ++m) {
#pragma unroll
        for (int j = 0; j < 4; ++j) {
            unsigned v = pm[m][j];
            unsigned gcode = ((unsigned)h * 16u + (63u - (v & 63u))) * 16u + (unsigned)c;
            v = (v & 0xFFFFFC00u) | (1023u - gcode);
#pragma unroll
            for (int off = 1; off < 16; off <<= 1) {
                unsigned o = (unsigned)__shfl_xor((int)v, off, 64);
                v = v < o ? o : v;
            }
            pm[m][j] = v;
        }
    }
    if (c == 0) {
#pragma unroll
        for (int m = 0; m < 4; ++m)
#pragma unroll
            for (int j = 0; j < 4; ++j) {
                const int row = rg * 64 + m * 16 + g * 4 + j;
                lds_comb[row * 4 + h] = pm[m][j];
            }
    }
    __syncthreads();

    // (7) combine across h; winner code + per-row loss term
    if (tid < 256) {
        uintx4 cm = *reinterpret_cast<const uintx4*>(&lds_comb[tid * 4]);
        unsigned v0 = cm[0] > cm[1] ? cm[0] : cm[1];
        unsigned v1 = cm[2] > cm[3] ? cm[2] : cm[3];
        unsigned v = v0 > v1 ? v0 : v1;
        lds_code[tid] = (int)(1023u - (v & 1023u));
        float tv = __builtin_bit_cast(float, v & 0xFFFFFC00u);
        float rl = fmaf(-2.0f, tv, 8.0f);
#pragma unroll
        for (int off = 1; off < 64; off <<= 1) rl += __shfl_xor(rl, off, 64);
        if (lane == 0) lds_rl[wave] = rl;
    }
    __syncthreads();

    // (8) coalesced output gather: 256 rows x 64 f32 dims as 16B chunks
#pragma unroll
    for (int it = 0; it < 4; ++it) {
        const int cidx = it * 1024 + tid;
        const int row = cidx >> 4, seg = cidx & 15;
        const int gc = lds_code[row];
        reinterpret_cast<f32x4*>(out)[(size_t)(blockIdx.x * 256 + row) * 16 + seg] =
            reinterpret_cast<const f32x4*>(emb)[(size_t)gc * 16 + seg];
    }
    if (tid == 0) {
        partials[blockIdx.x] = lds_rl[0] + lds_rl[1] + lds_rl[2] + lds_rl[3]
                             + lds_lnp[0] + lds_lnp[4] + lds_lnp[8] + lds_lnp[12];
    }
}

// one wave: sum 256 per-block partials (fixed order), scale, write loss scalar
__global__ __launch_bounds__(64) void vq_finalize(const float* __restrict__ partials,
                                                  float* __restrict__ loss_out) {
    const int lane = threadIdx.x;
    f32x4 p4 = reinterpret_cast<const f32x4*>(partials)[lane];
    float p = (p4[0] + p4[1]) + (p4[2] + p4[3]);
#pragma unroll
    for (int off = 1; off < 64; off <<= 1) p += __shfl_xor(p, off, 64);
    if (lane == 0) loss_out[0] = p * (1.25f / 4194304.f);
}

extern "C" void kernel_launch(void* const* d_in, const int* in_sizes, int n_in,
                              void* d_out, int out_size, void* d_ws, size_t ws_size,
                              hipStream_t stream) {
    const float* lat = (const float*)d_in[0];
    const float* emb = (const float*)d_in[1];
    float* out = (float*)d_out;
    float* partials = (float*)d_ws;                       // byte 0, 1 KB
    float* cvec_t = (float*)((char*)d_ws + 4096);         // 4 KB
    short* bfrag = (short*)((char*)d_ws + 8192);          // 128 KB

    vq_prep<<<64, 128, 0, stream>>>(emb, cvec_t, bfrag);
    vq_main<<<256, 1024, 0, stream>>>(lat, emb, cvec_t, bfrag, out, partials);
    vq_finalize<<<1, 64, 0, stream>>>(partials, out + (size_t)N_TOK * DIM);
}